// Round 10
// baseline (160.711 us; speedup 1.0000x reference)
//
#include <hip/hip_runtime.h>
#include <math.h>

// LeNet-5 fused forward, G=4 images per 256-thread block, 2048 blocks, f16 MFMA + fdot2.
// Round 10: round-9 structure, scratch-free phase-C offsets (computed, not table-lookup).
typedef _Float16 h16;
typedef h16  h8v __attribute__((ext_vector_type(8)));
typedef h16  h4v __attribute__((ext_vector_type(4)));
typedef h16  h2v __attribute__((ext_vector_type(2)));
typedef float f4v __attribute__((ext_vector_type(4)));
typedef unsigned int u32;

#if defined(__has_builtin)
#if __has_builtin(__builtin_amdgcn_fdot2)
#define FDOT2(a,b,c) __builtin_amdgcn_fdot2((a),(b),(c),false)
#endif
#endif
#ifndef FDOT2
#define FDOT2(a,b,c) ((c) + (float)(a).x*(float)(b).x + (float)(a).y*(float)(b).y)
#endif

// ws float offsets
#define WS_K1H  0       // 216 h16: folded C1+S2 6x6x6 packed f16 pairs
#define WS_B1   216     // 6 f32
#define WS_B3   224     // 16 f32
#define WS_W3H  240     // [6][16][48] f16 (C3 B^T, k=u*6+v, pad 36..47=0)
#define WS_W5H  2544    // [16][128][32] f16 (C5 B^T, k=r*5+c, pads 0)
#define WS_F6H  35312   // [96][128] f16 (F6 B^T, pads 0)
#define WS_RBFT 41456   // 840 f32: rbf transposed [10][84]

// LDS byte offsets. Lifetimes (6 barriers):
//  [0..960)       constants (whole kernel)
//  S2H  @960..14784   (B-write -> C-MFMA reads)          [4][6][16][18] f16
//  A5   @960..17600   (A5-build write -> D-MFMA reads; S2H dead)  [16][520] f16
//  HB   @960..6592    (E-epi -> F; A5 dead)              [16][88] f32
//  XPADH@14784..26304 (stage -> B)                       [4][36][40] f16
//  S4   @20160..25536 (C-epi -> A5-build; XPADH dead)    [4][16][42] f16
//  A6   @20160..24512 (D-epi -> E; S4 dead)              [16][136] f16
#define L_B3    0
#define L_C5B   64
#define L_F6B   576
#define L_S2H   960
#define L_A5    960
#define L_HB    960
#define L_XPADH 14784
#define L_S4    20160
#define L_A6    20160
#define LDS_TOTAL 26304

__device__ const unsigned char MASK16[16] = {7,14,28,56,49,35,15,30,60,57,51,39,27,54,45,63};

__device__ __forceinline__ float squash(float x) {
    float z = (2.0f / 3.0f) * x;
    float a = fabsf(z);
    float e = __expf(-2.0f * a);
    float t = (1.0f - e) * __builtin_amdgcn_rcpf(1.0f + e);
    return copysignf(1.7159f * t, z);
}

__global__ __launch_bounds__(256) void prep_kernel(
    const float* __restrict__ c1_w, const float* __restrict__ c1_b,
    const float* __restrict__ s2_w, const float* __restrict__ s2_b,
    const float* __restrict__ c3_w, const float* __restrict__ c3_b,
    const float* __restrict__ s4_w, const float* __restrict__ s4_b,
    const float* __restrict__ c5_w, const float* __restrict__ f6_w,
    const float* __restrict__ rbf_w,
    float* __restrict__ ws)
{
    const int gid = blockIdx.x * 256 + threadIdx.x;
    const int gstr = gridDim.x * 256;
    h16* K1H = (h16*)ws;
    for (int idx = gid; idx < 216; idx += gstr) {
        int c = idx / 36, r = idx - c * 36;
        int u = r / 6, v = r - u * 6;
        float s = 0.f;
        #pragma unroll
        for (int dy = 0; dy < 2; ++dy)
            #pragma unroll
            for (int dx = 0; dx < 2; ++dx) {
                int ky = u - dy, kx = v - dx;
                if (ky >= 0 && ky < 5 && kx >= 0 && kx < 5)
                    s += c1_w[(c * 5 + ky) * 5 + kx];
            }
        K1H[idx] = (h16)(0.25f * s * s2_w[c]);
    }
    if (gid < 6)  ws[WS_B1 + gid] = s2_w[gid] * c1_b[gid] + s2_b[gid];
    if (gid < 16) ws[WS_B3 + gid] = s4_w[gid] * c3_b[gid] + s4_b[gid];
    h16* W3H = (h16*)(ws + WS_W3H);
    for (int idx = gid; idx < 4608; idx += gstr) {
        int i = idx / 768, r = idx - i * 768;
        int n = r / 48, k = r - n * 48;
        float val = 0.f;
        if (k < 36) {
            int u = k / 6, v = k - u * 6;
            float s = 0.f;
            #pragma unroll
            for (int dy = 0; dy < 2; ++dy)
                #pragma unroll
                for (int dx = 0; dx < 2; ++dx) {
                    int ky = u - dy, kx = v - dx;
                    if (ky >= 0 && ky < 5 && kx >= 0 && kx < 5)
                        s += c3_w[((n * 6 + i) * 5 + ky) * 5 + kx];
                }
            val = ((MASK16[n] >> i) & 1) ? 0.25f * s4_w[n] * s : 0.f;
        }
        W3H[idx] = (h16)val;
    }
    h16* W5H = (h16*)(ws + WS_W5H);
    for (int idx = gid; idx < 65536; idx += gstr) {
        int i = idx >> 12, r = idx & 4095;
        int n = r >> 5, k = r & 31;
        float val = (n < 120 && k < 25) ? c5_w[n * 400 + i * 25 + k] : 0.f;
        W5H[idx] = (h16)val;
    }
    h16* F6H = (h16*)(ws + WS_F6H);
    for (int idx = gid; idx < 12288; idx += gstr) {
        int n = idx >> 7, k = idx & 127;
        float val = (n < 84 && k < 120) ? f6_w[n * 120 + k] : 0.f;
        F6H[idx] = (h16)val;
    }
    for (int idx = gid; idx < 840; idx += gstr) {
        int k = idx / 10, c = idx - k * 10;
        ws[WS_RBFT + c * 84 + k] = rbf_w[idx];
    }
}

__global__ __launch_bounds__(256, 6) void lenet_kernel(
    const float* __restrict__ x,
    const float* __restrict__ c5_b, const float* __restrict__ f6_b,
    const float* __restrict__ ws,
    float* __restrict__ out)
{
    __shared__ __align__(16) char smem[LDS_TOTAL];
    float* s_b3  = (float*)(smem + L_B3);
    float* s_c5b = (float*)(smem + L_C5B);
    float* s_f6b = (float*)(smem + L_F6B);
    h16*  XPADH  = (h16*)(smem + L_XPADH);
    h16*  S2H    = (h16*)(smem + L_S2H);
    h16*  S4     = (h16*)(smem + L_S4);
    h16*  A5     = (h16*)(smem + L_A5);
    h16*  A6     = (h16*)(smem + L_A6);
    float* HB    = (float*)(smem + L_HB);

    const int tid  = threadIdx.x;
    const int wave = __builtin_amdgcn_readfirstlane(tid >> 6);
    const int lane = tid & 63;
    const int quad = lane >> 4;
    const int lr   = lane & 15;

    // ---- stage constants + input (replicate pad, f16 packed pairs, pitch 40) ----
    if (tid < 16)  s_b3[tid] = ws[WS_B3 + tid];
    if (tid < 128) s_c5b[tid] = (tid < 120) ? c5_b[tid] : 0.f;
    if (tid < 96)  s_f6b[tid] = (tid < 84) ? f6_b[tid] : 0.f;
    const float* xb = x + (size_t)blockIdx.x * 4096;
    for (int idx = tid; idx < 2880; idx += 256) {
        int img = idx / 720, r2 = idx - img * 720;
        int u = r2 / 20, v2 = r2 - u * 20;
        int sy = min(max(u - 2, 0), 31);
        int c0 = min(max(2 * v2 - 2, 0), 31);
        int c1 = min(max(2 * v2 - 1, 0), 31);
        const float* xr = xb + img * 1024 + sy * 32;
        h2v hv; hv.x = (h16)xr[c0]; hv.y = (h16)xr[c1];
        *(h2v*)(XPADH + img * 1440 + u * 40 + 2 * v2) = hv;
    }
    __syncthreads();   // [1] XPADH + consts ready

    // ======== B: C1+S2+act via fdot2 -> S2H f16 ========
    {
        int py = tid >> 4, px = tid & 15;
        h2v win2[4][18];
        #pragma unroll
        for (int img = 0; img < 4; ++img) {
            const h16* basep = XPADH + img * 1440 + (2 * py) * 40 + 2 * px;
            #pragma unroll
            for (int u = 0; u < 6; ++u)
                #pragma unroll
                for (int p = 0; p < 3; ++p)
                    win2[img][u * 3 + p] = *(const h2v*)(basep + u * 40 + 2 * p);
        }
        const h2v* K1H = (const h2v*)ws;  // [6][18]
        #pragma unroll
        for (int c = 0; c < 6; ++c) {
            float bias = ws[WS_B1 + c];
            h2v wv[18];
            #pragma unroll
            for (int j = 0; j < 18; ++j) wv[j] = K1H[c * 18 + j];
            #pragma unroll
            for (int img = 0; img < 4; ++img) {
                float acc = bias;
                #pragma unroll
                for (int j = 0; j < 18; ++j)
                    acc = FDOT2(win2[img][j], wv[j], acc);
                S2H[img * 1728 + c * 288 + py * 18 + px] = (h16)squash(acc);
            }
        }
    }
    __syncthreads();   // [2] S2H ready

    // ======== C: C3+S4 via MFMA, A-fragments read DIRECTLY from S2H ========
    {
        const h16* W3H = (const h16*)(ws + WS_W3H);
        h8v w3a[6]; h4v w3b[6];
        #pragma unroll
        for (int i = 0; i < 6; ++i) {
            const h16* bbase = W3H + i * 768 + lr * 48;
            w3a[i] = *(const h8v*)(bbase + quad * 8);
            w3b[i] = *(const h4v*)(bbase + 32 + quad * 4);
        }
        // computed per-quad k-slice offsets (NO divergent-indexed arrays -> no scratch):
        // load j covers k=8*quad+2*j; halves offset = (k/6)*18 + (k%6)
        int o0, o1, o2, o3;
        {
            int k0 = 8 * quad;
            int u0 = k0 / 6,      v0 = k0 - u0 * 6;       o0 = u0 * 18 + v0;
            int k1 = k0 + 2;
            int u1 = k1 / 6,      v1 = k1 - u1 * 6;       o1 = u1 * 18 + v1;
            int k2 = k0 + 4;
            int u2 = k2 / 6,      v2 = k2 - u2 * 6;       o2 = u2 * 18 + v2;
            int k3 = k0 + 6;
            int u3 = k3 / 6,      v3 = k3 - u3 * 6;       o3 = u3 * 18 + v3;
        }
        // per-s row geometry: m = Mt*16+lr -> img,pos,py,px
        int baseh[3];
        #pragma unroll
        for (int s = 0; s < 3; ++s) {
            int Mt = wave + 4 * s;
            int m = Mt * 16 + lr; if (m > 143) m = 143;
            int img = m / 36, pos = m - img * 36;
            int py = pos / 6, px = pos - py * 6;
            baseh[s] = img * 1728 + (2 * py) * 18 + 2 * px;
        }
        f4v cacc[3] = {};
        for (int i = 0; i < 6; ++i) {
            #pragma unroll
            for (int s = 0; s < 3; ++s) {
                int Mt = wave + 4 * s;
                if (Mt < 9) {
                    const h16* bp = S2H + baseh[s] + i * 288;
                    union { u32 u[4]; h8v h; } av;
                    av.u[0] = *(const u32*)(bp + o0);
                    av.u[1] = *(const u32*)(bp + o1);
                    av.u[2] = *(const u32*)(bp + o2);
                    av.u[3] = *(const u32*)(bp + o3);
                    cacc[s] = __builtin_amdgcn_mfma_f32_16x16x32_f16(av.h, w3a[i], cacc[s], 0, 0, 0);
                    // k=32..35 (quad0 lanes matter; B is zero for k>=36 so other quads' A is don't-care)
                    union { u32 u[2]; h4v h; } av2;
                    av2.u[0] = *(const u32*)(bp + 92);
                    av2.u[1] = *(const u32*)(bp + 94);
                    cacc[s] = __builtin_amdgcn_mfma_f32_16x16x16f16(av2.h, w3b[i], cacc[s], 0, 0, 0);
                }
            }
        }
        // epilogue: squash -> S4 @ dead-XPADH region
        #pragma unroll
        for (int s = 0; s < 3; ++s) {
            int Mt = wave + 4 * s;
            if (Mt < 9) {
                #pragma unroll
                for (int r = 0; r < 4; ++r) {
                    int m = Mt * 16 + quad * 4 + r;
                    int img = m / 36, pos = m - img * 36;
                    float v = cacc[s][r] + s_b3[lr];
                    S4[img * 672 + lr * 42 + pos] = (h16)squash(v);
                }
            }
        }
    }
    __syncthreads();   // [3] S4 ready; all S2H reads done

    // ======== D: C5 via MFMA. GEMM [16 x 512] x [512 x 128] ========
    {
        // build A5 [16][520] (over dead S2H): thread = (m, i); reads S4 (disjoint region)
        {
            int m = tid >> 4, i = tid & 15;
            int img = m >> 2, q = m & 3, qy = q >> 1, qx = q & 1;
            const h16* s4b = S4 + img * 672 + i * 42 + qy * 6 + qx;
            h16* dst = A5 + m * 520 + i * 32;
            #pragma unroll
            for (int c = 0; c < 4; ++c) {
                h8v v;
                #pragma unroll
                for (int j = 0; j < 8; ++j) {
                    int k = c * 8 + j;
                    v[j] = (k < 25) ? s4b[(k / 5) * 6 + (k % 5)] : (h16)0.f;
                }
                *(h8v*)(dst + c * 8) = v;
            }
        }
        __syncthreads();   // [4] A5 ready
        const h16* W5H = (const h16*)(ws + WS_W5H);
        f4v dacc[2] = {};
        #pragma unroll 4
        for (int i = 0; i < 16; ++i) {
            h8v bf0 = *(const h8v*)(W5H + i * 4096 + (wave * 32 + lr) * 32 + quad * 8);
            h8v bf1 = *(const h8v*)(W5H + i * 4096 + (wave * 32 + 16 + lr) * 32 + quad * 8);
            h8v af0 = *(const h8v*)(A5 + lr * 520 + i * 32 + quad * 8);
            dacc[0] = __builtin_amdgcn_mfma_f32_16x16x32_f16(af0, bf0, dacc[0], 0, 0, 0);
            dacc[1] = __builtin_amdgcn_mfma_f32_16x16x32_f16(af0, bf1, dacc[1], 0, 0, 0);
        }
        // zero pad cols 120..127 of A6 (over dead S4)
        if (tid < 64) {
            int m = tid >> 2, j = tid & 3;
            *(u32*)(A6 + m * 136 + 120 + 2 * j) = 0u;
        }
        // epilogue, reference reshape: row=img*4+(n/30), col=(n%30)*4+q
        #pragma unroll
        for (int nt = 0; nt < 2; ++nt) {
            int n = wave * 32 + nt * 16 + lr;
            if (n < 120) {
                int tt = n / 30, cb = (n - tt * 30) * 4;
                float bias = s_c5b[n];
                #pragma unroll
                for (int r = 0; r < 4; ++r) {
                    int m = quad * 4 + r;
                    int img = m >> 2, q = m & 3;
                    A6[(img * 4 + tt) * 136 + cb + q] = (h16)(dacc[nt][r] + bias);
                }
            }
        }
    }
    __syncthreads();   // [5] A6 ready; all A5 reads done

    // ======== E: F6+act via MFMA. GEMM [16 x 128] x [128 x 96] ========
    {
        const h16* F6H = (const h16*)(ws + WS_F6H);
        f4v eacc[2] = {};
        #pragma unroll
        for (int kc = 0; kc < 4; ++kc) {
            h8v a8 = *(const h8v*)(A6 + lr * 136 + kc * 32 + quad * 8);
            h8v b0 = *(const h8v*)(F6H + (wave * 16 + lr) * 128 + kc * 32 + quad * 8);
            eacc[0] = __builtin_amdgcn_mfma_f32_16x16x32_f16(a8, b0, eacc[0], 0, 0, 0);
            if (wave < 2) {
                h8v b1 = *(const h8v*)(F6H + ((wave + 4) * 16 + lr) * 128 + kc * 32 + quad * 8);
                eacc[1] = __builtin_amdgcn_mfma_f32_16x16x32_f16(a8, b1, eacc[1], 0, 0, 0);
            }
        }
        {
            int n = wave * 16 + lr;   // 0..63 < 84
            float bias = s_f6b[n];
            #pragma unroll
            for (int r = 0; r < 4; ++r) {
                int m = quad * 4 + r;
                HB[m * 88 + n] = squash(eacc[0][r] + bias);   // HB over dead A5
            }
        }
        if (wave < 2) {
            int n = (wave + 4) * 16 + lr;  // 64..95
            if (n < 84) {
                float bias = s_f6b[n];
                #pragma unroll
                for (int r = 0; r < 4; ++r) {
                    int m = quad * 4 + r;
                    HB[m * 88 + n] = squash(eacc[1][r] + bias);
                }
            }
        }
    }
    __syncthreads();   // [6] HB ready

    // ======== F: RBF distances (VALU); prototypes from L2-resident rbfT ========
    if (tid < 160) {
        int m = tid / 10, cls = tid - m * 10;
        const float4* hr = (const float4*)(HB + m * 88);
        const float4* pr = (const float4*)(ws + WS_RBFT + cls * 84);
        float a = 0.f;
        #pragma unroll
        for (int u = 0; u < 21; ++u) {
            float4 hv = hr[u], pv = pr[u];
            float dx = hv.x - pv.x, dy = hv.y - pv.y;
            float dz = hv.z - pv.z, dw = hv.w - pv.w;
            a += dx * dx + dy * dy + dz * dz + dw * dw;
        }
        out[(size_t)blockIdx.x * 160 + tid] = a;
    }
}

extern "C" void kernel_launch(void* const* d_in, const int* in_sizes, int n_in,
                              void* d_out, int out_size, void* d_ws, size_t ws_size,
                              hipStream_t stream) {
    (void)n_in; (void)out_size; (void)ws_size;
    const float* x     = (const float*)d_in[0];
    const float* c1_w  = (const float*)d_in[1];
    const float* c1_b  = (const float*)d_in[2];
    const float* s2_w  = (const float*)d_in[3];
    const float* s2_b  = (const float*)d_in[4];
    const float* c3_w  = (const float*)d_in[5];
    const float* c3_b  = (const float*)d_in[6];
    const float* s4_w  = (const float*)d_in[7];
    const float* s4_b  = (const float*)d_in[8];
    const float* c5_w  = (const float*)d_in[9];
    const float* c5_b  = (const float*)d_in[10];
    const float* f6_w  = (const float*)d_in[11];
    const float* f6_b  = (const float*)d_in[12];
    const float* rbf_w = (const float*)d_in[13];
    float* out = (float*)d_out;
    float* ws  = (float*)d_ws;

    const int B = in_sizes[0] / 1024;   // 8192

    prep_kernel<<<256, 256, 0, stream>>>(c1_w, c1_b, s2_w, s2_b, c3_w, c3_b,
                                         s4_w, s4_b, c5_w, f6_w, rbf_w, ws);
    lenet_kernel<<<B / 4, 256, 0, stream>>>(x, c5_b, f6_b, ws, out);
}

// Round 11
// 143.809 us; speedup vs baseline: 1.1175x; 1.1175x over previous
//
#include <hip/hip_runtime.h>
#include <math.h>

// LeNet-5 fused forward, G=4 images per 256-thread block, 2048 blocks, f16 MFMA + fdot2.
// Round 11: phase C hand-unrolled, zero local arrays -> no scratch spill.
typedef _Float16 h16;
typedef h16  h8v __attribute__((ext_vector_type(8)));
typedef h16  h4v __attribute__((ext_vector_type(4)));
typedef h16  h2v __attribute__((ext_vector_type(2)));
typedef float f4v __attribute__((ext_vector_type(4)));
typedef unsigned int u32;

#if defined(__has_builtin)
#if __has_builtin(__builtin_amdgcn_fdot2)
#define FDOT2(a,b,c) __builtin_amdgcn_fdot2((a),(b),(c),false)
#endif
#endif
#ifndef FDOT2
#define FDOT2(a,b,c) ((c) + (float)(a).x*(float)(b).x + (float)(a).y*(float)(b).y)
#endif

// ws float offsets
#define WS_K1H  0       // 216 h16: folded C1+S2 6x6x6 packed f16 pairs
#define WS_B1   216     // 6 f32
#define WS_B3   224     // 16 f32
#define WS_W3H  240     // [6][16][48] f16 (C3 B^T, k=u*6+v, pad 36..47=0)
#define WS_W5H  2544    // [16][128][32] f16 (C5 B^T, k=r*5+c, pads 0)
#define WS_F6H  35312   // [96][128] f16 (F6 B^T, pads 0)
#define WS_RBFT 41456   // 840 f32: rbf transposed [10][84]

// LDS byte offsets (6 barriers; lifetimes as round 9)
#define L_B3    0
#define L_C5B   64
#define L_F6B   576
#define L_S2H   960
#define L_A5    960
#define L_HB    960
#define L_XPADH 14784
#define L_S4    20160
#define L_A6    20160
#define LDS_TOTAL 26304

__device__ const unsigned char MASK16[16] = {7,14,28,56,49,35,15,30,60,57,51,39,27,54,45,63};

__device__ __forceinline__ float squash(float x) {
    float z = (2.0f / 3.0f) * x;
    float a = fabsf(z);
    float e = __expf(-2.0f * a);
    float t = (1.0f - e) * __builtin_amdgcn_rcpf(1.0f + e);
    return copysignf(1.7159f * t, z);
}

__global__ __launch_bounds__(256) void prep_kernel(
    const float* __restrict__ c1_w, const float* __restrict__ c1_b,
    const float* __restrict__ s2_w, const float* __restrict__ s2_b,
    const float* __restrict__ c3_w, const float* __restrict__ c3_b,
    const float* __restrict__ s4_w, const float* __restrict__ s4_b,
    const float* __restrict__ c5_w, const float* __restrict__ f6_w,
    const float* __restrict__ rbf_w,
    float* __restrict__ ws)
{
    const int gid = blockIdx.x * 256 + threadIdx.x;
    const int gstr = gridDim.x * 256;
    h16* K1H = (h16*)ws;
    for (int idx = gid; idx < 216; idx += gstr) {
        int c = idx / 36, r = idx - c * 36;
        int u = r / 6, v = r - u * 6;
        float s = 0.f;
        #pragma unroll
        for (int dy = 0; dy < 2; ++dy)
            #pragma unroll
            for (int dx = 0; dx < 2; ++dx) {
                int ky = u - dy, kx = v - dx;
                if (ky >= 0 && ky < 5 && kx >= 0 && kx < 5)
                    s += c1_w[(c * 5 + ky) * 5 + kx];
            }
        K1H[idx] = (h16)(0.25f * s * s2_w[c]);
    }
    if (gid < 6)  ws[WS_B1 + gid] = s2_w[gid] * c1_b[gid] + s2_b[gid];
    if (gid < 16) ws[WS_B3 + gid] = s4_w[gid] * c3_b[gid] + s4_b[gid];
    h16* W3H = (h16*)(ws + WS_W3H);
    for (int idx = gid; idx < 4608; idx += gstr) {
        int i = idx / 768, r = idx - i * 768;
        int n = r / 48, k = r - n * 48;
        float val = 0.f;
        if (k < 36) {
            int u = k / 6, v = k - u * 6;
            float s = 0.f;
            #pragma unroll
            for (int dy = 0; dy < 2; ++dy)
                #pragma unroll
                for (int dx = 0; dx < 2; ++dx) {
                    int ky = u - dy, kx = v - dx;
                    if (ky >= 0 && ky < 5 && kx >= 0 && kx < 5)
                        s += c3_w[((n * 6 + i) * 5 + ky) * 5 + kx];
                }
            val = ((MASK16[n] >> i) & 1) ? 0.25f * s4_w[n] * s : 0.f;
        }
        W3H[idx] = (h16)val;
    }
    h16* W5H = (h16*)(ws + WS_W5H);
    for (int idx = gid; idx < 65536; idx += gstr) {
        int i = idx >> 12, r = idx & 4095;
        int n = r >> 5, k = r & 31;
        float val = (n < 120 && k < 25) ? c5_w[n * 400 + i * 25 + k] : 0.f;
        W5H[idx] = (h16)val;
    }
    h16* F6H = (h16*)(ws + WS_F6H);
    for (int idx = gid; idx < 12288; idx += gstr) {
        int n = idx >> 7, k = idx & 127;
        float val = (n < 84 && k < 120) ? f6_w[n * 120 + k] : 0.f;
        F6H[idx] = (h16)val;
    }
    for (int idx = gid; idx < 840; idx += gstr) {
        int k = idx / 10, c = idx - k * 10;
        ws[WS_RBFT + c * 84 + k] = rbf_w[idx];
    }
}

__global__ __launch_bounds__(256, 6) void lenet_kernel(
    const float* __restrict__ x,
    const float* __restrict__ c5_b, const float* __restrict__ f6_b,
    const float* __restrict__ ws,
    float* __restrict__ out)
{
    __shared__ __align__(16) char smem[LDS_TOTAL];
    float* s_b3  = (float*)(smem + L_B3);
    float* s_c5b = (float*)(smem + L_C5B);
    float* s_f6b = (float*)(smem + L_F6B);
    h16*  XPADH  = (h16*)(smem + L_XPADH);
    h16*  S2H    = (h16*)(smem + L_S2H);
    h16*  S4     = (h16*)(smem + L_S4);
    h16*  A5     = (h16*)(smem + L_A5);
    h16*  A6     = (h16*)(smem + L_A6);
    float* HB    = (float*)(smem + L_HB);

    const int tid  = threadIdx.x;
    const int wave = __builtin_amdgcn_readfirstlane(tid >> 6);
    const int lane = tid & 63;
    const int quad = lane >> 4;
    const int lr   = lane & 15;

    // ---- stage constants + input (replicate pad, f16 packed pairs, pitch 40) ----
    if (tid < 16)  s_b3[tid] = ws[WS_B3 + tid];
    if (tid < 128) s_c5b[tid] = (tid < 120) ? c5_b[tid] : 0.f;
    if (tid < 96)  s_f6b[tid] = (tid < 84) ? f6_b[tid] : 0.f;
    const float* xb = x + (size_t)blockIdx.x * 4096;
    for (int idx = tid; idx < 2880; idx += 256) {
        int img = idx / 720, r2 = idx - img * 720;
        int u = r2 / 20, v2 = r2 - u * 20;
        int sy = min(max(u - 2, 0), 31);
        int c0 = min(max(2 * v2 - 2, 0), 31);
        int c1 = min(max(2 * v2 - 1, 0), 31);
        const float* xr = xb + img * 1024 + sy * 32;
        h2v hv; hv.x = (h16)xr[c0]; hv.y = (h16)xr[c1];
        *(h2v*)(XPADH + img * 1440 + u * 40 + 2 * v2) = hv;
    }
    __syncthreads();   // [1] XPADH + consts ready

    // ======== B: C1+S2+act via fdot2 -> S2H f16 ========
    {
        int py = tid >> 4, px = tid & 15;
        h2v win2[4][18];
        #pragma unroll
        for (int img = 0; img < 4; ++img) {
            const h16* basep = XPADH + img * 1440 + (2 * py) * 40 + 2 * px;
            #pragma unroll
            for (int u = 0; u < 6; ++u)
                #pragma unroll
                for (int p = 0; p < 3; ++p)
                    win2[img][u * 3 + p] = *(const h2v*)(basep + u * 40 + 2 * p);
        }
        const h2v* K1H = (const h2v*)ws;  // [6][18]
        #pragma unroll
        for (int c = 0; c < 6; ++c) {
            float bias = ws[WS_B1 + c];
            h2v wv[18];
            #pragma unroll
            for (int j = 0; j < 18; ++j) wv[j] = K1H[c * 18 + j];
            #pragma unroll
            for (int img = 0; img < 4; ++img) {
                float acc = bias;
                #pragma unroll
                for (int j = 0; j < 18; ++j)
                    acc = FDOT2(win2[img][j], wv[j], acc);
                S2H[img * 1728 + c * 288 + py * 18 + px] = (h16)squash(acc);
            }
        }
    }
    __syncthreads();   // [2] S2H ready

    // ======== C: C3+S4 via MFMA, A-fragments direct from S2H; hand-unrolled, no arrays ========
    {
        const h16* W3H = (const h16*)(ws + WS_W3H);
        // computed per-quad k-slice offsets: load j covers k=8*quad+2*j; off=(k/6)*18+(k%6)
        int o0, o1, o2, o3;
        {
            int k0 = 8 * quad;
            int u0 = k0 / 6, v0 = k0 - u0 * 6;  o0 = u0 * 18 + v0;
            int k1 = k0 + 2;
            int u1 = k1 / 6, v1 = k1 - u1 * 6;  o1 = u1 * 18 + v1;
            int k2 = k0 + 4;
            int u2 = k2 / 6, v2 = k2 - u2 * 6;  o2 = u2 * 18 + v2;
            int k3 = k0 + 6;
            int u3 = k3 / 6, v3 = k3 - u3 * 6;  o3 = u3 * 18 + v3;
        }
        // row geometry for the three M-tiles (Mt = wave, wave+4, 8[wave0 only])
        int baseh0, baseh1, baseh2;
        {
            int m0 = wave * 16 + lr;
            int i0 = m0 / 36, p0 = m0 - i0 * 36;
            baseh0 = i0 * 1728 + (2 * (p0 / 6)) * 18 + 2 * (p0 % 6);
            int m1 = (wave + 4) * 16 + lr;
            int i1 = m1 / 36, p1 = m1 - i1 * 36;
            baseh1 = i1 * 1728 + (2 * (p1 / 6)) * 18 + 2 * (p1 % 6);
            int m2 = 128 + lr;   // Mt=8 (used by wave 0 only)
            int i2 = m2 / 36, p2 = m2 - i2 * 36;
            baseh2 = i2 * 1728 + (2 * (p2 / 6)) * 18 + 2 * (p2 % 6);
        }
        f4v cacc0 = {}, cacc1 = {}, cacc2 = {};
        const bool w0 = (wave == 0);
        #pragma unroll
        for (int i = 0; i < 6; ++i) {
            const h16* bbase = W3H + i * 768 + lr * 48;
            h8v w3a = *(const h8v*)(bbase + quad * 8);
            h4v w3b = *(const h4v*)(bbase + 32 + quad * 4);
            const h16* bp0 = S2H + baseh0 + i * 288;
            {
                union { u32 u[4]; h8v h; } av;
                av.u[0] = *(const u32*)(bp0 + o0);
                av.u[1] = *(const u32*)(bp0 + o1);
                av.u[2] = *(const u32*)(bp0 + o2);
                av.u[3] = *(const u32*)(bp0 + o3);
                cacc0 = __builtin_amdgcn_mfma_f32_16x16x32_f16(av.h, w3a, cacc0, 0, 0, 0);
                union { u32 u[2]; h4v h; } av2;
                av2.u[0] = *(const u32*)(bp0 + 92);
                av2.u[1] = *(const u32*)(bp0 + 94);
                cacc0 = __builtin_amdgcn_mfma_f32_16x16x16f16(av2.h, w3b, cacc0, 0, 0, 0);
            }
            const h16* bp1 = S2H + baseh1 + i * 288;
            {
                union { u32 u[4]; h8v h; } av;
                av.u[0] = *(const u32*)(bp1 + o0);
                av.u[1] = *(const u32*)(bp1 + o1);
                av.u[2] = *(const u32*)(bp1 + o2);
                av.u[3] = *(const u32*)(bp1 + o3);
                cacc1 = __builtin_amdgcn_mfma_f32_16x16x32_f16(av.h, w3a, cacc1, 0, 0, 0);
                union { u32 u[2]; h4v h; } av2;
                av2.u[0] = *(const u32*)(bp1 + 92);
                av2.u[1] = *(const u32*)(bp1 + 94);
                cacc1 = __builtin_amdgcn_mfma_f32_16x16x16f16(av2.h, w3b, cacc1, 0, 0, 0);
            }
            if (w0) {
                const h16* bp2 = S2H + baseh2 + i * 288;
                union { u32 u[4]; h8v h; } av;
                av.u[0] = *(const u32*)(bp2 + o0);
                av.u[1] = *(const u32*)(bp2 + o1);
                av.u[2] = *(const u32*)(bp2 + o2);
                av.u[3] = *(const u32*)(bp2 + o3);
                cacc2 = __builtin_amdgcn_mfma_f32_16x16x32_f16(av.h, w3a, cacc2, 0, 0, 0);
                union { u32 u[2]; h4v h; } av2;
                av2.u[0] = *(const u32*)(bp2 + 92);
                av2.u[1] = *(const u32*)(bp2 + 94);
                cacc2 = __builtin_amdgcn_mfma_f32_16x16x16f16(av2.h, w3b, cacc2, 0, 0, 0);
            }
        }
        // epilogue: squash -> S4 @ dead-XPADH region
        float b3v = s_b3[lr];
        {
            #pragma unroll
            for (int r = 0; r < 4; ++r) {
                int m = wave * 16 + quad * 4 + r;
                int img = m / 36, pos = m - img * 36;
                S4[img * 672 + lr * 42 + pos] = (h16)squash(cacc0[r] + b3v);
            }
            #pragma unroll
            for (int r = 0; r < 4; ++r) {
                int m = (wave + 4) * 16 + quad * 4 + r;
                int img = m / 36, pos = m - img * 36;
                S4[img * 672 + lr * 42 + pos] = (h16)squash(cacc1[r] + b3v);
            }
            if (w0) {
                #pragma unroll
                for (int r = 0; r < 4; ++r) {
                    int m = 128 + quad * 4 + r;
                    int img = m / 36, pos = m - img * 36;
                    S4[img * 672 + lr * 42 + pos] = (h16)squash(cacc2[r] + b3v);
                }
            }
        }
    }
    __syncthreads();   // [3] S4 ready; all S2H reads done

    // ======== D: C5 via MFMA. GEMM [16 x 512] x [512 x 128] ========
    {
        // build A5 [16][520] (over dead S2H): thread = (m, i); reads S4 (disjoint region)
        {
            int m = tid >> 4, i = tid & 15;
            int img = m >> 2, q = m & 3, qy = q >> 1, qx = q & 1;
            const h16* s4b = S4 + img * 672 + i * 42 + qy * 6 + qx;
            h16* dst = A5 + m * 520 + i * 32;
            #pragma unroll
            for (int c = 0; c < 4; ++c) {
                h8v v;
                #pragma unroll
                for (int j = 0; j < 8; ++j) {
                    int k = c * 8 + j;
                    v[j] = (k < 25) ? s4b[(k / 5) * 6 + (k % 5)] : (h16)0.f;
                }
                *(h8v*)(dst + c * 8) = v;
            }
        }
        __syncthreads();   // [4] A5 ready
        const h16* W5H = (const h16*)(ws + WS_W5H);
        f4v dacc0 = {}, dacc1 = {};
        #pragma unroll
        for (int i = 0; i < 16; ++i) {
            h8v bf0 = *(const h8v*)(W5H + i * 4096 + (wave * 32 + lr) * 32 + quad * 8);
            h8v bf1 = *(const h8v*)(W5H + i * 4096 + (wave * 32 + 16 + lr) * 32 + quad * 8);
            h8v af0 = *(const h8v*)(A5 + lr * 520 + i * 32 + quad * 8);
            dacc0 = __builtin_amdgcn_mfma_f32_16x16x32_f16(af0, bf0, dacc0, 0, 0, 0);
            dacc1 = __builtin_amdgcn_mfma_f32_16x16x32_f16(af0, bf1, dacc1, 0, 0, 0);
        }
        // zero pad cols 120..127 of A6 (over dead S4)
        if (tid < 64) {
            int m = tid >> 2, j = tid & 3;
            *(u32*)(A6 + m * 136 + 120 + 2 * j) = 0u;
        }
        // epilogue, reference reshape: row=img*4+(n/30), col=(n%30)*4+q
        {
            int n0 = wave * 32 + lr;
            if (n0 < 120) {
                int tt = n0 / 30, cb = (n0 - tt * 30) * 4;
                float bias = s_c5b[n0];
                #pragma unroll
                for (int r = 0; r < 4; ++r) {
                    int m = quad * 4 + r;
                    A6[((m >> 2) * 4 + tt) * 136 + cb + (m & 3)] = (h16)(dacc0[r] + bias);
                }
            }
            int n1 = wave * 32 + 16 + lr;
            if (n1 < 120) {
                int tt = n1 / 30, cb = (n1 - tt * 30) * 4;
                float bias = s_c5b[n1];
                #pragma unroll
                for (int r = 0; r < 4; ++r) {
                    int m = quad * 4 + r;
                    A6[((m >> 2) * 4 + tt) * 136 + cb + (m & 3)] = (h16)(dacc1[r] + bias);
                }
            }
        }
    }
    __syncthreads();   // [5] A6 ready; all A5 reads done

    // ======== E: F6+act via MFMA. GEMM [16 x 128] x [128 x 96] ========
    {
        const h16* F6H = (const h16*)(ws + WS_F6H);
        f4v eacc0 = {}, eacc1 = {};
        const bool w2 = (wave < 2);
        #pragma unroll
        for (int kc = 0; kc < 4; ++kc) {
            h8v a8 = *(const h8v*)(A6 + lr * 136 + kc * 32 + quad * 8);
            h8v b0 = *(const h8v*)(F6H + (wave * 16 + lr) * 128 + kc * 32 + quad * 8);
            eacc0 = __builtin_amdgcn_mfma_f32_16x16x32_f16(a8, b0, eacc0, 0, 0, 0);
            if (w2) {
                h8v b1 = *(const h8v*)(F6H + ((wave + 4) * 16 + lr) * 128 + kc * 32 + quad * 8);
                eacc1 = __builtin_amdgcn_mfma_f32_16x16x32_f16(a8, b1, eacc1, 0, 0, 0);
            }
        }
        {
            int n = wave * 16 + lr;   // 0..63 < 84
            float bias = s_f6b[n];
            #pragma unroll
            for (int r = 0; r < 4; ++r) {
                int m = quad * 4 + r;
                HB[m * 88 + n] = squash(eacc0[r] + bias);   // HB over dead A5
            }
        }
        if (w2) {
            int n = (wave + 4) * 16 + lr;  // 64..95
            if (n < 84) {
                float bias = s_f6b[n];
                #pragma unroll
                for (int r = 0; r < 4; ++r) {
                    int m = quad * 4 + r;
                    HB[m * 88 + n] = squash(eacc1[r] + bias);
                }
            }
        }
    }
    __syncthreads();   // [6] HB ready

    // ======== F: RBF distances (VALU); prototypes from L2-resident rbfT ========
    if (tid < 160) {
        int m = tid / 10, cls = tid - m * 10;
        const float4* hr = (const float4*)(HB + m * 88);
        const float4* pr = (const float4*)(ws + WS_RBFT + cls * 84);
        float a = 0.f;
        #pragma unroll
        for (int u = 0; u < 21; ++u) {
            float4 hv = hr[u], pv = pr[u];
            float dx = hv.x - pv.x, dy = hv.y - pv.y;
            float dz = hv.z - pv.z, dw = hv.w - pv.w;
            a += dx * dx + dy * dy + dz * dz + dw * dw;
        }
        out[(size_t)blockIdx.x * 160 + tid] = a;
    }
}

extern "C" void kernel_launch(void* const* d_in, const int* in_sizes, int n_in,
                              void* d_out, int out_size, void* d_ws, size_t ws_size,
                              hipStream_t stream) {
    (void)n_in; (void)out_size; (void)ws_size;
    const float* x     = (const float*)d_in[0];
    const float* c1_w  = (const float*)d_in[1];
    const float* c1_b  = (const float*)d_in[2];
    const float* s2_w  = (const float*)d_in[3];
    const float* s2_b  = (const float*)d_in[4];
    const float* c3_w  = (const float*)d_in[5];
    const float* c3_b  = (const float*)d_in[6];
    const float* s4_w  = (const float*)d_in[7];
    const float* s4_b  = (const float*)d_in[8];
    const float* c5_w  = (const float*)d_in[9];
    const float* c5_b  = (const float*)d_in[10];
    const float* f6_w  = (const float*)d_in[11];
    const float* f6_b  = (const float*)d_in[12];
    const float* rbf_w = (const float*)d_in[13];
    float* out = (float*)d_out;
    float* ws  = (float*)d_ws;

    const int B = in_sizes[0] / 1024;   // 8192

    prep_kernel<<<256, 256, 0, stream>>>(c1_w, c1_b, s2_w, s2_b, c3_w, c3_b,
                                         s4_w, s4_b, c5_w, f6_w, rbf_w, ws);
    lenet_kernel<<<B / 4, 256, 0, stream>>>(x, c5_b, f6_b, ws, out);
}